// Round 1
// 96.363 us; speedup vs baseline: 1.2634x; 1.2634x over previous
//
#include <hip/hip_runtime.h>
#include <hip/hip_bf16.h>
#include <math.h>

#define HD   2048
#define DD   128
#define TT   4096
#define BB   4
#define MT   (BB*TT)     // 16384 tokens
#define LSEG 64
#define SSEG 64
#define NCOL 256
#define SCALE_D 0.088388347648318447f  // 1/sqrt(128)

typedef _Float16 half8 __attribute__((ext_vector_type(8)));
typedef _Float16 half4v __attribute__((ext_vector_type(4)));
typedef float    f32x4 __attribute__((ext_vector_type(4)));

__device__ __forceinline__ float sigmf(float x){ return 1.f/(1.f+__expf(-x)); }

__device__ __forceinline__ void glds16(const void* g, void* l) {
  __builtin_amdgcn_global_load_lds(
      (const __attribute__((address_space(1))) unsigned int*)g,
      (__attribute__((address_space(3))) unsigned int*)l, 16, 0, 0);
}

// ---------------------------------------------------------------------------
// K_pre: pack B' = g (.) [sp_w | W_q] as fp16, n-major [256][2048], LINEAR
// storage. Per-col sums s_n, cb_n; we2 = g*w_eta; scal = {s_eta, cb_eta, 0, 0}
// ---------------------------------------------------------------------------
__global__ void k_pre(const float* __restrict__ ln_g, const float* __restrict__ ln_b,
                      const float* __restrict__ sp_w, const float* __restrict__ sp_b,
                      const float* __restrict__ W_qkv, const float* __restrict__ W_eta_w,
                      const float* __restrict__ W_eta_b,
                      _Float16* __restrict__ Bp, float* __restrict__ s_vec,
                      float* __restrict__ cb_vec, float* __restrict__ we2,
                      float* __restrict__ scal)
{
  __shared__ float red1[256], red2[256];
  int n = blockIdx.x, t = threadIdx.x;
  float sp = 0.f, cp = 0.f;
  if (n < NCOL) {
    for (int h = t; h < HD; h += 256) {
      float w = (n < DD) ? sp_w[(size_t)h*DD + n] : W_qkv[(size_t)h*384 + 256 + (n-DD)];
      float g = ln_g[h], b = ln_b[h];
      Bp[(size_t)n*HD + h] = (_Float16)(g*w);
      sp += g*w; cp += b*w;
    }
  } else {
    for (int h = t; h < HD; h += 256) {
      float w = W_eta_w[h];
      float g = ln_g[h], b = ln_b[h];
      we2[h] = g*w;
      sp += g*w; cp += b*w;
    }
  }
  red1[t] = sp; red2[t] = cp;
  __syncthreads();
  for (int o = 128; o > 0; o >>= 1) {
    if (t < o) { red1[t] += red1[t+o]; red2[t] += red2[t+o]; }
    __syncthreads();
  }
  if (t == 0) {
    if (n < NCOL) {
      s_vec[n]  = red1[0];
      cb_vec[n] = red2[0] + ((n < DD) ? sp_b[n] : 0.f);
    } else {
      scal[0] = red1[0];
      scal[1] = red2[0] + W_eta_b[0];
      scal[2] = 0.f; scal[3] = 0.f;
    }
  }
}

// ---------------------------------------------------------------------------
// K01 v2: fused LN-stats + GEMM + segment ops.
// Grid 256 (one block per segment), 512 threads = 8 waves (2M x 4N).
// BM=64 BN=256 BK=64 -> A (fp32 H) read ONCE per element (was twice).
// Pipeline: double-buffered sA/sB, ONE raw s_barrier per K-step,
// counted s_waitcnt vmcnt(2) so the 2 A-prefetch loads stay in flight
// across the barrier; B glds for kt+1 issued post-barrier (WAR-safe:
// last reader of that buffer passed the previous barrier) and drained
// only at the NEXT iteration's vmcnt(2) -> full-iteration latency cover.
// ---------------------------------------------------------------------------
__launch_bounds__(512, 2)
__global__ void k01(const float* __restrict__ H, const _Float16* __restrict__ Bp,
                    const float* __restrict__ s_vec, const float* __restrict__ cb_vec,
                    const float* __restrict__ we2, const float* __restrict__ scal,
                    const float* __restrict__ sum_q, const float* __restrict__ Mmat,
                    const float* __restrict__ temp,
                    float* __restrict__ Q_r, float* __restrict__ Zeta,
                    float* __restrict__ A_seg, float* __restrict__ eta_seg)
{
  __shared__ __align__(16) char pool[81920];   // sA 2x8K + sB 2x32K | sHm 64x260 f32
  __shared__ float we_s[HD];                   // 8 KB
  __shared__ float smu[64], srs[64], seta[64];
  __shared__ float sq_s[128], w64_s[64], Zs[128], red_s[4];
  __shared__ float eta_sh_s;
  _Float16* sA  = (_Float16*)pool;             // 2 bufs x [64 rows][8 chunks of 8]
  _Float16* sB  = (_Float16*)(pool + 16384);   // 2 bufs x [256 rows][8 chunks]
  float*    sHm = (float*)pool;                // epilogue alias [64][260]

  int tid = threadIdx.x;
  int seg = blockIdx.x;
  int b   = seg >> 6;
  int m0  = seg * 64;
  int w = tid >> 6, lane = tid & 63;
  int wr = w >> 2, wc = w & 3;
  int fcol = lane & 15, kq = lane >> 4;

  for (int i = tid; i < HD/4; i += 512)
    ((float4*)we_s)[i] = ((const float4*)we2)[i];
  if (tid < 128) sq_s[tid] = sum_q[tid];
  float scal0 = scal[0], scal1 = scal[1];
  __syncthreads();

  // A loader: thread -> row r_l, 8-float strip s8
  int r_l = tid >> 3, s8 = tid & 7;
  const float* aptr = H + (size_t)(m0 + r_l)*HD + s8*8;
  // B loader: 4 glds slots, XOR'd source chunk (dest linear)
  int bn[4], bsl[4];
#pragma unroll
  for (int i = 0; i < 4; ++i) {
    int idx = i*512 + tid;
    bn[i]  = idx >> 3;
    bsl[i] = (idx & 7) ^ (bn[i] & 7);
  }

  f32x4 acc[2][4];
#pragma unroll
  for (int i = 0; i < 2; ++i)
#pragma unroll
    for (int j = 0; j < 4; ++j) acc[i][j] = (f32x4){0.f,0.f,0.f,0.f};
  float s1 = 0.f, s2 = 0.f, se = 0.f;

  // prologue: A(0) -> regs, B(0) -> sB buf0. Queue: [paA x2, glds x4]
  float4 pa0 = *(const float4*)(aptr + 0);
  float4 pa1 = *(const float4*)(aptr + 4);
#pragma unroll
  for (int i = 0; i < 4; ++i)
    glds16(Bp + (size_t)bn[i]*HD + bsl[i]*8, sB + (size_t)(i*512 + tid)*8);

  for (int kt = 0; kt < 32; ++kt) {
    int cur = kt & 1;
    int k0 = kt*64;
    _Float16* sAc = sA + cur*4096;
    _Float16* sBc = sB + cur*16384;
    // stage A(kt): stats side-sums + fp16 convert + swizzled LDS write.
    // (compiler waits vmcnt(4) for pa here -> B glds stay in flight)
    {
      float v[8] = {pa0.x,pa0.y,pa0.z,pa0.w, pa1.x,pa1.y,pa1.z,pa1.w};
      const float4* wv4 = (const float4*)(we_s + k0 + s8*8);
      float4 u0 = wv4[0], u1 = wv4[1];
      float uu[8] = {u0.x,u0.y,u0.z,u0.w, u1.x,u1.y,u1.z,u1.w};
      half8 h0;
#pragma unroll
      for (int j = 0; j < 8; ++j) {
        s1 += v[j]; s2 += v[j]*v[j]; se += v[j]*uu[j];
        h0[j] = (_Float16)v[j];
      }
      *(half8*)&sAc[r_l*64 + (s8 ^ (r_l & 7))*8] = h0;
    }
    if (kt < 31) {
      // issue A(kt+1); queue: [glds B(kt) x4, A(kt+1) x2]
      const float* ap = aptr + (kt+1)*64;
      pa0 = *(const float4*)(ap + 0);
      pa1 = *(const float4*)(ap + 4);
      // B(kt) landed; A(kt+1) stays in flight across the barrier
      asm volatile("s_waitcnt vmcnt(2) lgkmcnt(0)" ::: "memory");
    } else {
      asm volatile("s_waitcnt vmcnt(0) lgkmcnt(0)" ::: "memory");
    }
    __builtin_amdgcn_s_barrier();
    __builtin_amdgcn_sched_barrier(0);
    if (kt < 31) {
      // B(kt+1) -> other buffer; drained at NEXT iteration's vmcnt(2)
      _Float16* sBn = sB + (cur^1)*16384;
      const _Float16* bsrc = Bp + (k0 + 64);
#pragma unroll
      for (int i = 0; i < 4; ++i)
        glds16(bsrc + (size_t)bn[i]*HD + bsl[i]*8, sBn + (size_t)(i*512 + tid)*8);
    }
#pragma unroll
    for (int ks = 0; ks < 2; ++ks) {
      half8 af[2], bf[4];
#pragma unroll
      for (int rt = 0; rt < 2; ++rt) {
        int r = wr*32 + rt*16 + fcol;
        int ch = (ks*4 + kq) ^ (r & 7);
        af[rt] = *(half8*)&sAc[r*64 + ch*8];
      }
#pragma unroll
      for (int ct = 0; ct < 4; ++ct) {
        int n = wc*64 + ct*16 + fcol;
        int ch = (ks*4 + kq) ^ (n & 7);
        bf[ct] = *(half8*)&sBc[n*64 + ch*8];
      }
#pragma unroll
      for (int rt = 0; rt < 2; ++rt)
#pragma unroll
        for (int ct = 0; ct < 4; ++ct)
          acc[rt][ct] = __builtin_amdgcn_mfma_f32_16x16x32_f16(af[rt], bf[ct], acc[rt][ct], 0,0,0);
    }
  }

  // row stats: reduce across the 8 strip-threads of each row (same wave)
  s1 += __shfl_xor(s1, 1); s1 += __shfl_xor(s1, 2); s1 += __shfl_xor(s1, 4);
  s2 += __shfl_xor(s2, 1); s2 += __shfl_xor(s2, 2); s2 += __shfl_xor(s2, 4);
  se += __shfl_xor(se, 1); se += __shfl_xor(se, 2); se += __shfl_xor(se, 4);
  if (s8 == 0) {
    float mu   = s1 * (1.f/HD);
    float var  = s2 * (1.f/HD) - mu*mu;
    float rstd = rsqrtf(var + 1e-5f);
    smu[r_l] = mu; srs[r_l] = rstd;
    seta[r_l] = rstd*(se - mu*scal0) + scal1;
  }
  __syncthreads();   // stats visible; all MFMA LDS reads done -> pool reusable

  // epilogue: LN affine -> sHm (cols 0..255)
#pragma unroll
  for (int ct = 0; ct < 4; ++ct) {
    int nl = wc*64 + ct*16 + fcol;
    float sn = s_vec[nl], cbn = cb_vec[nl];
#pragma unroll
    for (int rt = 0; rt < 2; ++rt)
#pragma unroll
      for (int r = 0; r < 4; ++r) {
        int m = wr*32 + rt*16 + kq*4 + r;
        sHm[m*260 + nl] = srs[m]*(acc[rt][ct][r] - smu[m]*sn) + cbn;
      }
  }
  __syncthreads();   // sHm ready

  // coalesced Q_r writes (cols 128..255)
#pragma unroll
  for (int j = 0; j < 4; ++j) {
    int idx = j*512 + tid;
    int row = idx >> 5, c4 = (idx & 31)*4;
    *(float4*)&Q_r[(size_t)(m0 + row)*DD + c4] = *(float4*)&sHm[row*260 + 128 + c4];
  }

  // ---- segment ops on H_mem (cols 0..127) ----
  if (w == 0) {
    float sc = 0.f;
    const float4* hrow = (const float4*)&sHm[lane*260];
#pragma unroll
    for (int d4 = 0; d4 < 32; ++d4) {
      float4 hv = hrow[d4];
      float4 qv = *(const float4*)&sq_s[d4*4];
      sc += hv.x*qv.x + hv.y*qv.y + hv.z*qv.z + hv.w*qv.w;
    }
    sc *= SCALE_D;
    float mx = sc;
    for (int o = 32; o > 0; o >>= 1) mx = fmaxf(mx, __shfl_xor(mx, o));
    float e = __expf(sc - mx);
    float sm = e;
    for (int o = 32; o > 0; o >>= 1) sm += __shfl_xor(sm, o);
    w64_s[lane] = e / sm;
  } else if (w == 1) {
    float ev = seta[lane];
    for (int o = 32; o > 0; o >>= 1) ev = fmaxf(ev, __shfl_xor(ev, o));
    if (lane == 0) { float es = sigmf(ev); eta_sh_s = es; eta_seg[seg] = es; }
  }
  __syncthreads();   // w64_s, eta_sh_s ready

  // Z[d] + Zeta
  if (tid < 128) {
    float z = 0.f;
    for (int l = 0; l < 64; ++l) z += w64_s[l]*sHm[l*260 + tid];
    Zs[tid] = z;
    Zeta[(size_t)seg*DD + tid] = z * eta_sh_s;
  }
  __syncthreads();   // Zs ready

  // write-attn scores over K=128 + softmax
  float sc2 = 0.f;
  if (tid < 128) {
    const float4* mrow = (const float4*)(Mmat + ((size_t)b*DD + tid)*DD);
#pragma unroll
    for (int d4 = 0; d4 < 32; ++d4) {
      float4 mv = mrow[d4];
      sc2 += mv.x*Zs[d4*4] + mv.y*Zs[d4*4+1] + mv.z*Zs[d4*4+2] + mv.w*Zs[d4*4+3];
    }
    sc2 *= SCALE_D * __expf(temp[0]);
    float mx = sc2;
    for (int o = 32; o > 0; o >>= 1) mx = fmaxf(mx, __shfl_xor(mx, o));
    if (lane == 0) red_s[w] = mx;
  }
  __syncthreads();
  float ev2 = 0.f;
  if (tid < 128) {
    float mx = fmaxf(red_s[0], red_s[1]);
    ev2 = __expf(sc2 - mx);
    float sm = ev2;
    for (int o = 32; o > 0; o >>= 1) sm += __shfl_xor(sm, o);
    if (lane == 0) red_s[2 + w] = sm;
  }
  __syncthreads();
  if (tid < 128) {
    float smt = red_s[2] + red_s[3];
    A_seg[(size_t)seg*DD + tid] = ev2 / smt;
  }
}

// ---------------------------------------------------------------------------
// K2b: DeltaM (k-chunk of 32 per block), M_new, row rnorms, norm_sq atomic.
// ---------------------------------------------------------------------------
__global__ void k2b(const float* __restrict__ A_seg, const float* __restrict__ Zeta,
                    const float* __restrict__ eta_seg, const float* __restrict__ Mmat,
                    const float* __restrict__ eta_ch,
                    float* __restrict__ M_new, float* __restrict__ rns_arr,
                    float* __restrict__ scal)
{
  __shared__ float As[64][33];
  __shared__ __align__(16) float Zsl[64*128];
  __shared__ float rowp[32][8];
  __shared__ float eta_av;
  __shared__ float redb[4];
  int tid = threadIdx.x;
  int b = blockIdx.x >> 2, kq = blockIdx.x & 3;
  for (int i = tid; i < 64*32; i += 256) {
    int s = i >> 5, j = i & 31;
    As[s][j] = A_seg[((size_t)b*SSEG + s)*DD + kq*32 + j];
  }
  const float4* z4 = (const float4*)(Zeta + (size_t)b*SSEG*DD);
  float4* zs4 = (float4*)Zsl;
  for (int i = tid; i < 64*32; i += 256) zs4[i] = z4[i];
  if (tid < 64) {
    float ev = eta_seg[(size_t)b*SSEG + tid];
    for (int o=32;o>0;o>>=1) ev += __shfl_xor(ev, o);
    if (tid == 0) eta_av = ev * (1.f/SSEG);
  }
  __syncthreads();
  int kl = tid & 31, dg = tid >> 5;
  int k = kq*32 + kl, d0 = dg*16;
  float dm[16];
#pragma unroll
  for (int j=0;j<16;j++) dm[j]=0.f;
  for (int s = 0; s < 64; ++s) {
    float a = As[s][kl];
    const float* zr = &Zsl[s*128 + d0];
#pragma unroll
    for (int j=0;j<16;j++) dm[j] += a * zr[j];
  }
  float nsq = 0.f;
#pragma unroll
  for (int j=0;j<16;j++) nsq += dm[j]*dm[j];
  float eav = eta_av;
  float mn[16];
  float ss = 0.f;
#pragma unroll
  for (int j=0;j<16;j++) {
    int d = d0 + j;
    float gate = eav * sigmf(eta_ch[d]);
    float v = (1.f - gate)*Mmat[((size_t)b*DD + k)*DD + d] + dm[j]*(1.f/SSEG);
    mn[j] = v; ss += v*v;
  }
#pragma unroll
  for (int j=0;j<16;j+=4) {
    float4 v4; v4.x=mn[j]; v4.y=mn[j+1]; v4.z=mn[j+2]; v4.w=mn[j+3];
    *(float4*)&M_new[((size_t)b*DD + k)*DD + d0 + j] = v4;
  }
  rowp[kl][dg] = ss;
  for (int o=1;o<64;o<<=1) nsq += __shfl_xor(nsq, o);
  if ((tid&63)==0) redb[tid>>6] = nsq;
  __syncthreads();
  if (tid == 0) atomicAdd(&scal[2], redb[0]+redb[1]+redb[2]+redb[3]);
  if (tid < 32) {
    float t2 = 0.f;
#pragma unroll
    for (int g=0; g<8; ++g) t2 += rowp[tid][g];
    float nrm = sqrtf(t2);
    rns_arr[(size_t)b*DD + kq*32 + tid] = 1.f / fmaxf(nrm, 1e-12f);
  }
}

// ---------------------------------------------------------------------------
// K2d: diversity loss partials.
// ---------------------------------------------------------------------------
__global__ void k2d(const float* __restrict__ M_new, const float* __restrict__ rns_arr,
                    float* __restrict__ scal)
{
  __shared__ float kr[4][128];
  __shared__ float redb[4];
  int tid = threadIdx.x;
  int b = blockIdx.x >> 5, kq = blockIdx.x & 31;
  for (int i = tid; i < 4*128; i += 256) {
    int ki = i >> 7, d = i & 127;
    kr[ki][d] = M_new[((size_t)b*DD + kq*4 + ki)*DD + d];
  }
  __syncthreads();
  int j = tid & 127, kh = tid >> 7;
  const float* mj = &M_new[((size_t)b*DD + j)*DD];
  float rj = rns_arr[(size_t)b*DD + j];
  float dv = 0.f;
#pragma unroll
  for (int ki2 = 0; ki2 < 2; ++ki2) {
    int kil = kh*2 + ki2;
    int kk = kq*4 + kil;
    float dot = 0.f;
    for (int d = 0; d < 128; d += 4) {
      float4 a = *(const float4*)(mj + d);
      dot += a.x*kr[kil][d] + a.y*kr[kil][d+1] + a.z*kr[kil][d+2] + a.w*kr[kil][d+3];
    }
    if (kk != j) {
      float sv = dot * rj * rns_arr[(size_t)b*DD + kk];
      dv += sv*sv;
    }
  }
  for (int o=1;o<64;o<<=1) dv += __shfl_xor(dv, o);
  if ((tid&63)==0) redb[tid>>6] = dv;
  __syncthreads();
  if (tid==0) atomicAdd(&scal[3], redb[0]+redb[1]+redb[2]+redb[3]);
}

// ---------------------------------------------------------------------------
// K3: read attention via MFMA fp16 (fp32 softmax/accum).
// ---------------------------------------------------------------------------
__launch_bounds__(256, 1)
__global__ void k3(const float* __restrict__ Q_r, const float* __restrict__ M_new,
                   const float* __restrict__ scal, float* __restrict__ out)
{
  __shared__ __align__(16) _Float16 Mq[128*132];  // [key][d]   (QK B-frags)
  __shared__ __align__(16) _Float16 Mt[128*136];  // [d][key]   (PV B-frags)
  __shared__ __align__(16) _Float16 Ps[64*132];   // [token][key] (PV A-frags)
  int tid = threadIdx.x;
  int b = blockIdx.x >> 6, tile = blockIdx.x & 63;
  int t0 = tile*64;
  if (blockIdx.x == 0 && tid == 0) {
    float loss = 0.01f*(scal[2]*(1.f/SSEG)) + 0.1f*(scal[3]*(1.f/(BB*DD*DD)));
    out[(size_t)MT*DD] = loss;
  }
  const float4* m4 = (const float4*)(M_new + (size_t)b*DD*DD);
#pragma unroll
  for (int it = 0; it < 4; ++it) {
    int sb = it*256 + tid;
    int rb = sb & 31, cb = sb >> 5;
    int r0 = rb*4, c0 = cb*4;
    float a[4][4];
#pragma unroll
    for (int j = 0; j < 4; ++j) {
      float4 v = m4[(size_t)(r0+j)*32 + cb];
      a[j][0]=v.x; a[j][1]=v.y; a[j][2]=v.z; a[j][3]=v.w;
    }
#pragma unroll
    for (int j = 0; j < 4; ++j) {
      half4v h; h.x=(_Float16)a[j][0]; h.y=(_Float16)a[j][1];
                h.z=(_Float16)a[j][2]; h.w=(_Float16)a[j][3];
      *(half4v*)&Mq[(r0+j)*132 + c0] = h;
    }
#pragma unroll
    for (int j2 = 0; j2 < 4; ++j2) {
      half4v h; h.x=(_Float16)a[0][j2]; h.y=(_Float16)a[1][j2];
                h.z=(_Float16)a[2][j2]; h.w=(_Float16)a[3][j2];
      *(half4v*)&Mt[(c0+j2)*136 + r0] = h;
    }
  }
  int w = tid >> 6, lane = tid & 63;
  int fcol = lane & 15, kq = lane >> 4;
  int tokA = t0 + w*16 + fcol;
  size_t qbase = ((size_t)b*TT + tokA)*DD;
  half8 af[4];
#pragma unroll
  for (int ks = 0; ks < 4; ++ks) {
    float4 q0 = *(const float4*)&Q_r[qbase + ks*32 + kq*8];
    float4 q1 = *(const float4*)&Q_r[qbase + ks*32 + kq*8 + 4];
    half8 h;
    h[0]=(_Float16)q0.x; h[1]=(_Float16)q0.y; h[2]=(_Float16)q0.z; h[3]=(_Float16)q0.w;
    h[4]=(_Float16)q1.x; h[5]=(_Float16)q1.y; h[6]=(_Float16)q1.z; h[7]=(_Float16)q1.w;
    af[ks] = h;
  }
  __syncthreads();
  f32x4 sacc[8];
#pragma unroll
  for (int nt = 0; nt < 8; ++nt) sacc[nt] = (f32x4){0.f,0.f,0.f,0.f};
#pragma unroll
  for (int nt = 0; nt < 8; ++nt)
#pragma unroll
    for (int ks = 0; ks < 4; ++ks) {
      half8 bf = *(half8*)&Mq[(nt*16 + fcol)*132 + ks*32 + kq*8];
      sacc[nt] = __builtin_amdgcn_mfma_f32_16x16x32_f16(af[ks], bf, sacc[nt], 0,0,0);
    }
#pragma unroll
  for (int nt = 0; nt < 8; ++nt)
#pragma unroll
    for (int r = 0; r < 4; ++r) sacc[nt][r] *= 2.f;
  float mx[4], sm[4];
#pragma unroll
  for (int r = 0; r < 4; ++r) {
    float m = sacc[0][r];
#pragma unroll
    for (int nt = 1; nt < 8; ++nt) m = fmaxf(m, sacc[nt][r]);
#pragma unroll
    for (int o = 1; o < 16; o <<= 1) m = fmaxf(m, __shfl_xor(m, o));
    mx[r] = m;
  }
#pragma unroll
  for (int r = 0; r < 4; ++r) sm[r] = 0.f;
#pragma unroll
  for (int nt = 0; nt < 8; ++nt)
#pragma unroll
    for (int r = 0; r < 4; ++r) {
      float e = __expf(sacc[nt][r] - mx[r]);
      sacc[nt][r] = e; sm[r] += e;
    }
#pragma unroll
  for (int r = 0; r < 4; ++r) {
    float s = sm[r];
#pragma unroll
    for (int o = 1; o < 16; o <<= 1) s += __shfl_xor(s, o);
    sm[r] = 1.f / s;
  }
#pragma unroll
  for (int nt = 0; nt < 8; ++nt)
#pragma unroll
    for (int r = 0; r < 4; ++r) {
      int tk = w*16 + kq*4 + r;
      Ps[tk*132 + nt*16 + fcol] = (_Float16)(sacc[nt][r]*sm[r]);
    }
  __syncthreads();
  half8 pf[4];
#pragma unroll
  for (int ks = 0; ks < 4; ++ks)
    pf[ks] = *(half8*)&Ps[(w*16 + fcol)*132 + ks*32 + kq*8];
  f32x4 cacc[8];
#pragma unroll
  for (int nt = 0; nt < 8; ++nt) cacc[nt] = (f32x4){0.f,0.f,0.f,0.f};
#pragma unroll
  for (int nt = 0; nt < 8; ++nt)
#pragma unroll
    for (int ks = 0; ks < 4; ++ks) {
      half8 bf = *(half8*)&Mt[(nt*16 + fcol)*136 + ks*32 + kq*8];
      cacc[nt] = __builtin_amdgcn_mfma_f32_16x16x32_f16(pf[ks], bf, cacc[nt], 0,0,0);
    }
#pragma unroll
  for (int nt = 0; nt < 8; ++nt)
#pragma unroll
    for (int r = 0; r < 4; ++r) {
      int tk = t0 + w*16 + kq*4 + r;
      out[((size_t)b*TT + tk)*DD + nt*16 + fcol] = cacc[nt][r];
    }
}

// ---------------------------------------------------------------------------
extern "C" void kernel_launch(void* const* d_in, const int* in_sizes, int n_in,
                              void* d_out, int out_size, void* d_ws, size_t ws_size,
                              hipStream_t stream)
{
  (void)in_sizes; (void)n_in; (void)out_size; (void)ws_size;
  const float* H       = (const float*)d_in[0];
  const float* Mmat    = (const float*)d_in[1];
  const float* ln_g    = (const float*)d_in[2];
  const float* ln_b    = (const float*)d_in[3];
  const float* W_eta_w = (const float*)d_in[4];
  const float* W_eta_b = (const float*)d_in[5];
  const float* sum_q   = (const float*)d_in[6];
  const float* sp_w    = (const float*)d_in[7];
  const float* sp_b    = (const float*)d_in[8];
  const float* eta_ch  = (const float*)d_in[9];
  const float* temp    = (const float*)d_in[10];
  const float* W_qkv   = (const float*)d_in[11];
  float* out           = (float*)d_out;

  char* wsb = (char*)d_ws;
  size_t off = 0;
  auto alloc = [&](size_t bytes) -> void* {
    void* p = wsb + off;
    off = (off + bytes + 255) & ~(size_t)255;
    return p;
  };
  _Float16* Bp   = (_Float16*)alloc((size_t)NCOL*HD*2);
  float* s_vec   = (float*)alloc(NCOL*4);
  float* cb_vec  = (float*)alloc(NCOL*4);
  float* we2     = (float*)alloc(HD*4);
  float* scal    = (float*)alloc(4*4);
  float* Q_r     = (float*)alloc((size_t)MT*DD*4);
  float* Zeta    = (float*)alloc((size_t)BB*SSEG*DD*4);
  float* A_seg   = (float*)alloc((size_t)BB*SSEG*DD*4);
  float* eta_seg = (float*)alloc((size_t)BB*SSEG*4);
  float* M_new   = (float*)alloc((size_t)BB*DD*DD*4);
  float* rns_arr = (float*)alloc((size_t)BB*DD*4);

  hipLaunchKernelGGL(k_pre, dim3(NCOL+1), dim3(256), 0, stream,
                     ln_g, ln_b, sp_w, sp_b, W_qkv, W_eta_w, W_eta_b,
                     Bp, s_vec, cb_vec, we2, scal);
  hipLaunchKernelGGL(k01, dim3(MT/64), dim3(512), 0, stream,
                     H, Bp, s_vec, cb_vec, we2, scal, sum_q, Mmat, temp,
                     Q_r, Zeta, A_seg, eta_seg);
  hipLaunchKernelGGL(k2b, dim3(16), dim3(256), 0, stream,
                     A_seg, Zeta, eta_seg, Mmat, eta_ch, M_new, rns_arr, scal);
  hipLaunchKernelGGL(k2d, dim3(128), dim3(256), 0, stream,
                     M_new, rns_arr, scal);
  hipLaunchKernelGGL(k3, dim3(256), dim3(256), 0, stream,
                     Q_r, M_new, scal, out);
}

// Round 2
// 87.061 us; speedup vs baseline: 1.3983x; 1.1068x over previous
//
#include <hip/hip_runtime.h>
#include <hip/hip_bf16.h>
#include <math.h>

#define HD   2048
#define DD   128
#define TT   4096
#define BB   4
#define MT   (BB*TT)     // 16384 tokens
#define LSEG 64
#define SSEG 64
#define NCOL 256
#define SCALE_D 0.088388347648318447f  // 1/sqrt(128)

typedef _Float16 half8 __attribute__((ext_vector_type(8)));
typedef _Float16 half4v __attribute__((ext_vector_type(4)));
typedef float    f32x4 __attribute__((ext_vector_type(4)));

__device__ __forceinline__ float sigmf(float x){ return 1.f/(1.f+__expf(-x)); }

__device__ __forceinline__ void glds16(const void* g, void* l) {
  __builtin_amdgcn_global_load_lds(
      (const __attribute__((address_space(1))) unsigned int*)g,
      (__attribute__((address_space(3))) unsigned int*)l, 16, 0, 0);
}

// ---------------------------------------------------------------------------
// K_pre: pack B' = g (.) [sp_w | W_q] as fp16, n-major [256][2048], LINEAR
// storage. Per-col sums s_n, cb_n; we2 = g*w_eta; scal = {s_eta, cb_eta, 0, 0}
// ---------------------------------------------------------------------------
__global__ void k_pre(const float* __restrict__ ln_g, const float* __restrict__ ln_b,
                      const float* __restrict__ sp_w, const float* __restrict__ sp_b,
                      const float* __restrict__ W_qkv, const float* __restrict__ W_eta_w,
                      const float* __restrict__ W_eta_b,
                      _Float16* __restrict__ Bp, float* __restrict__ s_vec,
                      float* __restrict__ cb_vec, float* __restrict__ we2,
                      float* __restrict__ scal)
{
  __shared__ float red1[256], red2[256];
  int n = blockIdx.x, t = threadIdx.x;
  float sp = 0.f, cp = 0.f;
  if (n < NCOL) {
    for (int h = t; h < HD; h += 256) {
      float w = (n < DD) ? sp_w[(size_t)h*DD + n] : W_qkv[(size_t)h*384 + 256 + (n-DD)];
      float g = ln_g[h], b = ln_b[h];
      Bp[(size_t)n*HD + h] = (_Float16)(g*w);
      sp += g*w; cp += b*w;
    }
  } else {
    for (int h = t; h < HD; h += 256) {
      float w = W_eta_w[h];
      float g = ln_g[h], b = ln_b[h];
      we2[h] = g*w;
      sp += g*w; cp += b*w;
    }
  }
  red1[t] = sp; red2[t] = cp;
  __syncthreads();
  for (int o = 128; o > 0; o >>= 1) {
    if (t < o) { red1[t] += red1[t+o]; red2[t] += red2[t+o]; }
    __syncthreads();
  }
  if (t == 0) {
    if (n < NCOL) {
      s_vec[n]  = red1[0];
      cb_vec[n] = red2[0] + ((n < DD) ? sp_b[n] : 0.f);
    } else {
      scal[0] = red1[0];
      scal[1] = red2[0] + W_eta_b[0];
      scal[2] = 0.f; scal[3] = 0.f;
    }
  }
}

// ---------------------------------------------------------------------------
// K01 v3: fused LN-stats + GEMM + segment ops.
// Grid 256 (one block per segment), 512 threads = 8 waves (2M x 4N).
// BM=64 BN=256 BK=64.
// Pipeline v3: 2-deep A register prefetch (even/odd sets, static regs via
// manual x2 unroll) + TRIPLE-buffered sB. Both A(kt+2) and B(kt+2) are
// issued in iter kt -> ~2 full iterations of latency coverage (vs 1 before,
// which left ~500cy HBM-latency stalls at every compiler vmcnt for pa).
// Counted vmcnt: steady-state queue at the pre-barrier wait is
// [B(kt)x4, paA(kt+1)x2, B(kt+1)x4, paA(kt+2)x2]; draining through B(kt)
// leaves 8 -> s_waitcnt vmcnt(8). Tail: kt=30 -> 6, kt=31 -> 0.
// ---------------------------------------------------------------------------
__launch_bounds__(512, 2)
__global__ void k01(const float* __restrict__ H, const _Float16* __restrict__ Bp,
                    const float* __restrict__ s_vec, const float* __restrict__ cb_vec,
                    const float* __restrict__ we2, const float* __restrict__ scal,
                    const float* __restrict__ sum_q, const float* __restrict__ Mmat,
                    const float* __restrict__ temp,
                    float* __restrict__ Q_r, float* __restrict__ Zeta,
                    float* __restrict__ A_seg, float* __restrict__ eta_seg)
{
  __shared__ __align__(16) char pool[114688]; // sA 2x8K + sB 3x32K | sHm 64x260 f32
  __shared__ float we_s[HD];                  // 8 KB
  __shared__ float smu[64], srs[64], seta[64];
  __shared__ float sq_s[128], w64_s[64], Zs[128], red_s[4];
  __shared__ float eta_sh_s;
  _Float16* sA  = (_Float16*)pool;            // 2 bufs x [64 rows][8 chunks of 8]
  _Float16* sB  = (_Float16*)(pool + 16384);  // 3 bufs x [256 rows][8 chunks]
  float*    sHm = (float*)pool;               // epilogue alias [64][260]

  int tid = threadIdx.x;
  int seg = blockIdx.x;
  int b   = seg >> 6;
  int m0  = seg * 64;
  int w = tid >> 6, lane = tid & 63;
  int wr = w >> 2, wc = w & 3;
  int fcol = lane & 15, kq = lane >> 4;

  for (int i = tid; i < HD/4; i += 512)
    ((float4*)we_s)[i] = ((const float4*)we2)[i];
  if (tid < 128) sq_s[tid] = sum_q[tid];
  float scal0 = scal[0], scal1 = scal[1];
  __syncthreads();

  // A loader: thread -> row r_l, 8-float strip s8
  int r_l = tid >> 3, s8 = tid & 7;
  const float* aptr = H + (size_t)(m0 + r_l)*HD + s8*8;
  // B loader: 4 glds slots, XOR'd source chunk (dest linear)
  int bn[4], bsl[4];
#pragma unroll
  for (int i = 0; i < 4; ++i) {
    int idx = i*512 + tid;
    bn[i]  = idx >> 3;
    bsl[i] = (idx & 7) ^ (bn[i] & 7);
  }

  f32x4 acc[2][4];
#pragma unroll
  for (int i = 0; i < 2; ++i)
#pragma unroll
    for (int j = 0; j < 4; ++j) acc[i][j] = (f32x4){0.f,0.f,0.f,0.f};
  float s1 = 0.f, s2 = 0.f, se = 0.f;

  // prologue in steady-state issue order: paA(0), B(0), paA(1), B(1)
  float4 paE0 = *(const float4*)(aptr + 0);
  float4 paE1 = *(const float4*)(aptr + 4);
#pragma unroll
  for (int i = 0; i < 4; ++i)
    glds16(Bp + (size_t)bn[i]*HD + bsl[i]*8, sB + (size_t)(i*512 + tid)*8);
  float4 paO0 = *(const float4*)(aptr + 64);
  float4 paO1 = *(const float4*)(aptr + 68);
#pragma unroll
  for (int i = 0; i < 4; ++i)
    glds16(Bp + (size_t)bn[i]*HD + 64 + bsl[i]*8,
           sB + 16384 + (size_t)(i*512 + tid)*8);

  int cur3 = 0;   // kt % 3

#define KSTEP(KT, P0, P1, VMASM, PREFETCH, BISSUE)                            \
  {                                                                           \
    _Float16* sAc = sA + ((KT)&1)*4096;                                       \
    _Float16* sBc = sB + cur3*16384;                                          \
    int k0 = (KT)*64;                                                         \
    float v[8] = {P0.x,P0.y,P0.z,P0.w, P1.x,P1.y,P1.z,P1.w};                  \
    if (PREFETCH) {                                                           \
      const float* ap_ = aptr + ((KT)+2)*64;                                  \
      P0 = *(const float4*)(ap_ + 0);                                         \
      P1 = *(const float4*)(ap_ + 4);                                         \
    }                                                                         \
    {                                                                         \
      const float4* wv4 = (const float4*)(we_s + k0 + s8*8);                  \
      float4 u0 = wv4[0], u1 = wv4[1];                                        \
      float uu[8] = {u0.x,u0.y,u0.z,u0.w, u1.x,u1.y,u1.z,u1.w};               \
      half8 h0;                                                               \
      _Pragma("unroll")                                                       \
      for (int j = 0; j < 8; ++j) {                                           \
        s1 += v[j]; s2 += v[j]*v[j]; se += v[j]*uu[j];                        \
        h0[j] = (_Float16)v[j];                                               \
      }                                                                       \
      *(half8*)&sAc[r_l*64 + (s8 ^ (r_l & 7))*8] = h0;                        \
    }                                                                         \
    asm volatile(VMASM ::: "memory");                                         \
    __builtin_amdgcn_s_barrier();                                             \
    __builtin_amdgcn_sched_barrier(0);                                        \
    if (BISSUE) {                                                             \
      int wb3 = cur3 + 2; if (wb3 >= 3) wb3 -= 3;                             \
      _Float16* sBn = sB + wb3*16384;                                         \
      const _Float16* bsrc = Bp + (k0 + 128);                                 \
      _Pragma("unroll")                                                       \
      for (int i = 0; i < 4; ++i)                                             \
        glds16(bsrc + (size_t)bn[i]*HD + bsl[i]*8,                            \
               sBn + (size_t)(i*512 + tid)*8);                                \
      __builtin_amdgcn_sched_barrier(0);                                      \
    }                                                                         \
    __builtin_amdgcn_s_setprio(1);                                            \
    _Pragma("unroll")                                                         \
    for (int ks = 0; ks < 2; ++ks) {                                          \
      half8 af[2], bf[4];                                                     \
      _Pragma("unroll")                                                       \
      for (int rt = 0; rt < 2; ++rt) {                                        \
        int r = wr*32 + rt*16 + fcol;                                         \
        int ch = (ks*4 + kq) ^ (r & 7);                                       \
        af[rt] = *(half8*)&sAc[r*64 + ch*8];                                  \
      }                                                                       \
      _Pragma("unroll")                                                       \
      for (int ct = 0; ct < 4; ++ct) {                                        \
        int n = wc*64 + ct*16 + fcol;                                         \
        int ch = (ks*4 + kq) ^ (n & 7);                                       \
        bf[ct] = *(half8*)&sBc[n*64 + ch*8];                                  \
      }                                                                       \
      _Pragma("unroll")                                                       \
      for (int rt = 0; rt < 2; ++rt)                                          \
        _Pragma("unroll")                                                     \
        for (int ct = 0; ct < 4; ++ct)                                        \
          acc[rt][ct] = __builtin_amdgcn_mfma_f32_16x16x32_f16(af[rt], bf[ct], acc[rt][ct], 0,0,0); \
    }                                                                         \
    __builtin_amdgcn_s_setprio(0);                                            \
    cur3 += 1; if (cur3 >= 3) cur3 -= 3;                                      \
  }

#pragma unroll 1
  for (int kp = 0; kp < 15; ++kp) {
    KSTEP(2*kp,   paE0, paE1, "s_waitcnt vmcnt(8) lgkmcnt(0)", 1, 1)
    KSTEP(2*kp+1, paO0, paO1, "s_waitcnt vmcnt(8) lgkmcnt(0)", 1, 1)
  }
  KSTEP(30, paE0, paE1, "s_waitcnt vmcnt(6) lgkmcnt(0)", 0, 0)
  KSTEP(31, paO0, paO1, "s_waitcnt vmcnt(0) lgkmcnt(0)", 0, 0)
#undef KSTEP

  // row stats: reduce across the 8 strip-threads of each row (same wave)
  s1 += __shfl_xor(s1, 1); s1 += __shfl_xor(s1, 2); s1 += __shfl_xor(s1, 4);
  s2 += __shfl_xor(s2, 1); s2 += __shfl_xor(s2, 2); s2 += __shfl_xor(s2, 4);
  se += __shfl_xor(se, 1); se += __shfl_xor(se, 2); se += __shfl_xor(se, 4);
  if (s8 == 0) {
    float mu   = s1 * (1.f/HD);
    float var  = s2 * (1.f/HD) - mu*mu;
    float rstd = rsqrtf(var + 1e-5f);
    smu[r_l] = mu; srs[r_l] = rstd;
    seta[r_l] = rstd*(se - mu*scal0) + scal1;
  }
  __syncthreads();   // stats visible; all MFMA LDS reads done -> pool reusable

  // epilogue: LN affine -> sHm (cols 0..255)
#pragma unroll
  for (int ct = 0; ct < 4; ++ct) {
    int nl = wc*64 + ct*16 + fcol;
    float sn = s_vec[nl], cbn = cb_vec[nl];
#pragma unroll
    for (int rt = 0; rt < 2; ++rt)
#pragma unroll
      for (int r = 0; r < 4; ++r) {
        int m = wr*32 + rt*16 + kq*4 + r;
        sHm[m*260 + nl] = srs[m]*(acc[rt][ct][r] - smu[m]*sn) + cbn;
      }
  }
  __syncthreads();   // sHm ready

  // coalesced Q_r writes (cols 128..255)
#pragma unroll
  for (int j = 0; j < 4; ++j) {
    int idx = j*512 + tid;
    int row = idx >> 5, c4 = (idx & 31)*4;
    *(float4*)&Q_r[(size_t)(m0 + row)*DD + c4] = *(float4*)&sHm[row*260 + 128 + c4];
  }

  // ---- segment ops on H_mem (cols 0..127) ----
  if (w == 0) {
    float sc = 0.f;
    const float4* hrow = (const float4*)&sHm[lane*260];
#pragma unroll
    for (int d4 = 0; d4 < 32; ++d4) {
      float4 hv = hrow[d4];
      float4 qv = *(const float4*)&sq_s[d4*4];
      sc += hv.x*qv.x + hv.y*qv.y + hv.z*qv.z + hv.w*qv.w;
    }
    sc *= SCALE_D;
    float mx = sc;
    for (int o = 32; o > 0; o >>= 1) mx = fmaxf(mx, __shfl_xor(mx, o));
    float e = __expf(sc - mx);
    float sm = e;
    for (int o = 32; o > 0; o >>= 1) sm += __shfl_xor(sm, o);
    w64_s[lane] = e / sm;
  } else if (w == 1) {
    float ev = seta[lane];
    for (int o = 32; o > 0; o >>= 1) ev = fmaxf(ev, __shfl_xor(ev, o));
    if (lane == 0) { float es = sigmf(ev); eta_sh_s = es; eta_seg[seg] = es; }
  }
  __syncthreads();   // w64_s, eta_sh_s ready

  // Z[d] + Zeta
  if (tid < 128) {
    float z = 0.f;
    for (int l = 0; l < 64; ++l) z += w64_s[l]*sHm[l*260 + tid];
    Zs[tid] = z;
    Zeta[(size_t)seg*DD + tid] = z * eta_sh_s;
  }
  __syncthreads();   // Zs ready

  // write-attn scores over K=128 + softmax
  float sc2 = 0.f;
  if (tid < 128) {
    const float4* mrow = (const float4*)(Mmat + ((size_t)b*DD + tid)*DD);
#pragma unroll
    for (int d4 = 0; d4 < 32; ++d4) {
      float4 mv = mrow[d4];
      sc2 += mv.x*Zs[d4*4] + mv.y*Zs[d4*4+1] + mv.z*Zs[d4*4+2] + mv.w*Zs[d4*4+3];
    }
    sc2 *= SCALE_D * __expf(temp[0]);
    float mx = sc2;
    for (int o = 32; o > 0; o >>= 1) mx = fmaxf(mx, __shfl_xor(mx, o));
    if (lane == 0) red_s[w] = mx;
  }
  __syncthreads();
  float ev2 = 0.f;
  if (tid < 128) {
    float mx = fmaxf(red_s[0], red_s[1]);
    ev2 = __expf(sc2 - mx);
    float sm = ev2;
    for (int o = 32; o > 0; o >>= 1) sm += __shfl_xor(sm, o);
    if (lane == 0) red_s[2 + w] = sm;
  }
  __syncthreads();
  if (tid < 128) {
    float smt = red_s[2] + red_s[3];
    A_seg[(size_t)seg*DD + tid] = ev2 / smt;
  }
}

// ---------------------------------------------------------------------------
// K2b: DeltaM (k-chunk of 32 per block), M_new, row rnorms, norm_sq atomic.
// ---------------------------------------------------------------------------
__global__ void k2b(const float* __restrict__ A_seg, const float* __restrict__ Zeta,
                    const float* __restrict__ eta_seg, const float* __restrict__ Mmat,
                    const float* __restrict__ eta_ch,
                    float* __restrict__ M_new, float* __restrict__ rns_arr,
                    float* __restrict__ scal)
{
  __shared__ float As[64][33];
  __shared__ __align__(16) float Zsl[64*128];
  __shared__ float rowp[32][8];
  __shared__ float eta_av;
  __shared__ float redb[4];
  int tid = threadIdx.x;
  int b = blockIdx.x >> 2, kq = blockIdx.x & 3;
  for (int i = tid; i < 64*32; i += 256) {
    int s = i >> 5, j = i & 31;
    As[s][j] = A_seg[((size_t)b*SSEG + s)*DD + kq*32 + j];
  }
  const float4* z4 = (const float4*)(Zeta + (size_t)b*SSEG*DD);
  float4* zs4 = (float4*)Zsl;
  for (int i = tid; i < 64*32; i += 256) zs4[i] = z4[i];
  if (tid < 64) {
    float ev = eta_seg[(size_t)b*SSEG + tid];
    for (int o=32;o>0;o>>=1) ev += __shfl_xor(ev, o);
    if (tid == 0) eta_av = ev * (1.f/SSEG);
  }
  __syncthreads();
  int kl = tid & 31, dg = tid >> 5;
  int k = kq*32 + kl, d0 = dg*16;
  float dm[16];
#pragma unroll
  for (int j=0;j<16;j++) dm[j]=0.f;
  for (int s = 0; s < 64; ++s) {
    float a = As[s][kl];
    const float* zr = &Zsl[s*128 + d0];
#pragma unroll
    for (int j=0;j<16;j++) dm[j] += a * zr[j];
  }
  float nsq = 0.f;
#pragma unroll
  for (int j=0;j<16;j++) nsq += dm[j]*dm[j];
  float eav = eta_av;
  float mn[16];
  float ss = 0.f;
#pragma unroll
  for (int j=0;j<16;j++) {
    int d = d0 + j;
    float gate = eav * sigmf(eta_ch[d]);
    float v = (1.f - gate)*Mmat[((size_t)b*DD + k)*DD + d] + dm[j]*(1.f/SSEG);
    mn[j] = v; ss += v*v;
  }
#pragma unroll
  for (int j=0;j<16;j+=4) {
    float4 v4; v4.x=mn[j]; v4.y=mn[j+1]; v4.z=mn[j+2]; v4.w=mn[j+3];
    *(float4*)&M_new[((size_t)b*DD + k)*DD + d0 + j] = v4;
  }
  rowp[kl][dg] = ss;
  for (int o=1;o<64;o<<=1) nsq += __shfl_xor(nsq, o);
  if ((tid&63)==0) redb[tid>>6] = nsq;
  __syncthreads();
  if (tid == 0) atomicAdd(&scal[2], redb[0]+redb[1]+redb[2]+redb[3]);
  if (tid < 32) {
    float t2 = 0.f;
#pragma unroll
    for (int g=0; g<8; ++g) t2 += rowp[tid][g];
    float nrm = sqrtf(t2);
    rns_arr[(size_t)b*DD + kq*32 + tid] = 1.f / fmaxf(nrm, 1e-12f);
  }
}

// ---------------------------------------------------------------------------
// K2d: diversity loss partials.
// ---------------------------------------------------------------------------
__global__ void k2d(const float* __restrict__ M_new, const float* __restrict__ rns_arr,
                    float* __restrict__ scal)
{
  __shared__ float kr[4][128];
  __shared__ float redb[4];
  int tid = threadIdx.x;
  int b = blockIdx.x >> 5, kq = blockIdx.x & 31;
  for (int i = tid; i < 4*128; i += 256) {
    int ki = i >> 7, d = i & 127;
    kr[ki][d] = M_new[((size_t)b*DD + kq*4 + ki)*DD + d];
  }
  __syncthreads();
  int j = tid & 127, kh = tid >> 7;
  const float* mj = &M_new[((size_t)b*DD + j)*DD];
  float rj = rns_arr[(size_t)b*DD + j];
  float dv = 0.f;
#pragma unroll
  for (int ki2 = 0; ki2 < 2; ++ki2) {
    int kil = kh*2 + ki2;
    int kk = kq*4 + kil;
    float dot = 0.f;
    for (int d = 0; d < 128; d += 4) {
      float4 a = *(const float4*)(mj + d);
      dot += a.x*kr[kil][d] + a.y*kr[kil][d+1] + a.z*kr[kil][d+2] + a.w*kr[kil][d+3];
    }
    if (kk != j) {
      float sv = dot * rj * rns_arr[(size_t)b*DD + kk];
      dv += sv*sv;
    }
  }
  for (int o=1;o<64;o<<=1) dv += __shfl_xor(dv, o);
  if ((tid&63)==0) redb[tid>>6] = dv;
  __syncthreads();
  if (tid==0) atomicAdd(&scal[3], redb[0]+redb[1]+redb[2]+redb[3]);
}

// ---------------------------------------------------------------------------
// K3: read attention via MFMA fp16 (fp32 softmax/accum).
// ---------------------------------------------------------------------------
__launch_bounds__(256, 1)
__global__ void k3(const float* __restrict__ Q_r, const float* __restrict__ M_new,
                   const float* __restrict__ scal, float* __restrict__ out)
{
  __shared__ __align__(16) _Float16 Mq[128*132];  // [key][d]   (QK B-frags)
  __shared__ __align__(16) _Float16 Mt[128*136];  // [d][key]   (PV B-frags)
  __shared__ __align__(16) _Float16 Ps[64*132];   // [token][key] (PV A-frags)
  int tid = threadIdx.x;
  int b = blockIdx.x >> 6, tile = blockIdx.x & 63;
  int t0 = tile*64;
  if (blockIdx.x == 0 && tid == 0) {
    float loss = 0.01f*(scal[2]*(1.f/SSEG)) + 0.1f*(scal[3]*(1.f/(BB*DD*DD)));
    out[(size_t)MT*DD] = loss;
  }
  const float4* m4 = (const float4*)(M_new + (size_t)b*DD*DD);
#pragma unroll
  for (int it = 0; it < 4; ++it) {
    int sb = it*256 + tid;
    int rb = sb & 31, cb = sb >> 5;
    int r0 = rb*4, c0 = cb*4;
    float a[4][4];
#pragma unroll
    for (int j = 0; j < 4; ++j) {
      float4 v = m4[(size_t)(r0+j)*32 + cb];
      a[j][0]=v.x; a[j][1]=v.y; a[j][2]=v.z; a[j][3]=v.w;
    }
#pragma unroll
    for (int j = 0; j < 4; ++j) {
      half4v h; h.x=(_Float16)a[j][0]; h.y=(_Float16)a[j][1];
                h.z=(_Float16)a[j][2]; h.w=(_Float16)a[j][3];
      *(half4v*)&Mq[(r0+j)*132 + c0] = h;
    }
#pragma unroll
    for (int j2 = 0; j2 < 4; ++j2) {
      half4v h; h.x=(_Float16)a[0][j2]; h.y=(_Float16)a[1][j2];
                h.z=(_Float16)a[2][j2]; h.w=(_Float16)a[3][j2];
      *(half4v*)&Mt[(c0+j2)*136 + r0] = h;
    }
  }
  int w = tid >> 6, lane = tid & 63;
  int fcol = lane & 15, kq = lane >> 4;
  int tokA = t0 + w*16 + fcol;
  size_t qbase = ((size_t)b*TT + tokA)*DD;
  half8 af[4];
#pragma unroll
  for (int ks = 0; ks < 4; ++ks) {
    float4 q0 = *(const float4*)&Q_r[qbase + ks*32 + kq*8];
    float4 q1 = *(const float4*)&Q_r[qbase + ks*32 + kq*8 + 4];
    half8 h;
    h[0]=(_Float16)q0.x; h[1]=(_Float16)q0.y; h[2]=(_Float16)q0.z; h[3]=(_Float16)q0.w;
    h[4]=(_Float16)q1.x; h[5]=(_Float16)q1.y; h[6]=(_Float16)q1.z; h[7]=(_Float16)q1.w;
    af[ks] = h;
  }
  __syncthreads();
  f32x4 sacc[8];
#pragma unroll
  for (int nt = 0; nt < 8; ++nt) sacc[nt] = (f32x4){0.f,0.f,0.f,0.f};
#pragma unroll
  for (int nt = 0; nt < 8; ++nt)
#pragma unroll
    for (int ks = 0; ks < 4; ++ks) {
      half8 bf = *(half8*)&Mq[(nt*16 + fcol)*132 + ks*32 + kq*8];
      sacc[nt] = __builtin_amdgcn_mfma_f32_16x16x32_f16(af[ks], bf, sacc[nt], 0,0,0);
    }
#pragma unroll
  for (int nt = 0; nt < 8; ++nt)
#pragma unroll
    for (int r = 0; r < 4; ++r) sacc[nt][r] *= 2.f;
  float mx[4], sm[4];
#pragma unroll
  for (int r = 0; r < 4; ++r) {
    float m = sacc[0][r];
#pragma unroll
    for (int nt = 1; nt < 8; ++nt) m = fmaxf(m, sacc[nt][r]);
#pragma unroll
    for (int o = 1; o < 16; o <<= 1) m = fmaxf(m, __shfl_xor(m, o));
    mx[r] = m;
  }
#pragma unroll
  for (int r = 0; r < 4; ++r) sm[r] = 0.f;
#pragma unroll
  for (int nt = 0; nt < 8; ++nt)
#pragma unroll
    for (int r = 0; r < 4; ++r) {
      float e = __expf(sacc[nt][r] - mx[r]);
      sacc[nt][r] = e; sm[r] += e;
    }
#pragma unroll
  for (int r = 0; r < 4; ++r) {
    float s = sm[r];
#pragma unroll
    for (int o = 1; o < 16; o <<= 1) s += __shfl_xor(s, o);
    sm[r] = 1.f / s;
  }
#pragma unroll
  for (int nt = 0; nt < 8; ++nt)
#pragma unroll
    for (int r = 0; r < 4; ++r) {
      int tk = w*16 + kq*4 + r;
      Ps[tk*132 + nt*16 + fcol] = (_Float16)(sacc[nt][r]*sm[r]);
    }
  __syncthreads();
  half8 pf[4];
#pragma unroll
  for (int ks = 0; ks < 4; ++ks)
    pf[ks] = *(half8*)&Ps[(w*16 + fcol)*132 + ks*32 + kq*8];
  f32x4 cacc[8];
#pragma unroll
  for (int nt = 0; nt < 8; ++nt) cacc[nt] = (f32x4){0.f,0.f,0.f,0.f};
#pragma unroll
  for (int nt = 0; nt < 8; ++nt)
#pragma unroll
    for (int ks = 0; ks < 4; ++ks) {
      half8 bf = *(half8*)&Mt[(nt*16 + fcol)*136 + ks*32 + kq*8];
      cacc[nt] = __builtin_amdgcn_mfma_f32_16x16x32_f16(pf[ks], bf, cacc[nt], 0,0,0);
    }
#pragma unroll
  for (int nt = 0; nt < 8; ++nt)
#pragma unroll
    for (int r = 0; r < 4; ++r) {
      int tk = t0 + w*16 + kq*4 + r;
      out[((size_t)b*TT + tk)*DD + nt*16 + fcol] = cacc[nt][r];
    }
}

// ---------------------------------------------------------------------------
extern "C" void kernel_launch(void* const* d_in, const int* in_sizes, int n_in,
                              void* d_out, int out_size, void* d_ws, size_t ws_size,
                              hipStream_t stream)
{
  (void)in_sizes; (void)n_in; (void)out_size; (void)ws_size;
  const float* H       = (const float*)d_in[0];
  const float* Mmat    = (const float*)d_in[1];
  const float* ln_g    = (const float*)d_in[2];
  const float* ln_b    = (const float*)d_in[3];
  const float* W_eta_w = (const float*)d_in[4];
  const float* W_eta_b = (const float*)d_in[5];
  const float* sum_q   = (const float*)d_in[6];
  const float* sp_w    = (const float*)d_in[7];
  const float* sp_b    = (const float*)d_in[8];
  const float* eta_ch  = (const float*)d_in[9];
  const float* temp    = (const float*)d_in[10];
  const float* W_qkv   = (const float*)d_in[11];
  float* out           = (float*)d_out;

  char* wsb = (char*)d_ws;
  size_t off = 0;
  auto alloc = [&](size_t bytes) -> void* {
    void* p = wsb + off;
    off = (off + bytes + 255) & ~(size_t)255;
    return p;
  };
  _Float16* Bp   = (_Float16*)alloc((size_t)NCOL*HD*2);
  float* s_vec   = (float*)alloc(NCOL*4);
  float* cb_vec  = (float*)alloc(NCOL*4);
  float* we2     = (float*)alloc(HD*4);
  float* scal    = (float*)alloc(4*4);
  float* Q_r     = (float*)alloc((size_t)MT*DD*4);
  float* Zeta    = (float*)alloc((size_t)BB*SSEG*DD*4);
  float* A_seg   = (float*)alloc((size_t)BB*SSEG*DD*4);
  float* eta_seg = (float*)alloc((size_t)BB*SSEG*4);
  float* M_new   = (float*)alloc((size_t)BB*DD*DD*4);
  float* rns_arr = (float*)alloc((size_t)BB*DD*4);

  hipLaunchKernelGGL(k_pre, dim3(NCOL+1), dim3(256), 0, stream,
                     ln_g, ln_b, sp_w, sp_b, W_qkv, W_eta_w, W_eta_b,
                     Bp, s_vec, cb_vec, we2, scal);
  hipLaunchKernelGGL(k01, dim3(MT/64), dim3(512), 0, stream,
                     H, Bp, s_vec, cb_vec, we2, scal, sum_q, Mmat, temp,
                     Q_r, Zeta, A_seg, eta_seg);
  hipLaunchKernelGGL(k2b, dim3(16), dim3(256), 0, stream,
                     A_seg, Zeta, eta_seg, Mmat, eta_ch, M_new, rns_arr, scal);
  hipLaunchKernelGGL(k2d, dim3(128), dim3(256), 0, stream,
                     M_new, rns_arr, scal);
  hipLaunchKernelGGL(k3, dim3(256), dim3(256), 0, stream,
                     Q_r, M_new, scal, out);
}